// Round 9
// baseline (150.257 us; speedup 1.0000x reference)
//
#include <hip/hip_runtime.h>
#include <hip/hip_bf16.h>

#define Bn 4
#define Nn 512
#define Tn 10
#define Fn 516      // N + 4
#define MH 128      // MSG_HID
#define MD 32       // MSG_DIM
#define UH 128      // UPD_HID
#define OD 4        // OUT_DIM

#define JSPLIT 128
#define JPB (Nn / JSPLIT)   // 4 j's per block
#define XTF (Tn * Fn)       // 5160 floats per (b,j) x-row

typedef __attribute__((ext_vector_type(4))) short short4v;  // 4 bf16 = 2 VGPRs
typedef __attribute__((ext_vector_type(8))) short short8v;
typedef __attribute__((ext_vector_type(4))) float floatx4;

static __device__ inline unsigned pk2(float a, float b) {
  union { __hip_bfloat162 h; unsigned u; } cv;
  cv.h = __float22bfloat162_rn(make_float2(a, b));
  return cv.u;
}
static __device__ inline short4v pack4(float a, float b, float c, float d) {
  union { short4v s; unsigned u[2]; } cv;
  cv.u[0] = pk2(a, b);
  cv.u[1] = pk2(c, d);
  return cv.s;
}

// K=16 bf16 MFMA. A/B frag: lane(ln,q) elem e -> k = 4q+e. D: row m = 4q+r, col n = ln.
#if __has_builtin(__builtin_amdgcn_mfma_f32_16x16x16bf16_1k)
static __device__ inline floatx4 MFMA16(short4v a, short4v b, floatx4 c) {
  return __builtin_amdgcn_mfma_f32_16x16x16bf16_1k(a, b, c, 0, 0, 0);
}
#else
// Fallback: K=16 data in elems 0-3 of the K=32 op pairs k-wise; zero tail is exact.
static __device__ inline floatx4 MFMA16(short4v a, short4v b, floatx4 c) {
  short8v a8 = {a[0], a[1], a[2], a[3], 0, 0, 0, 0};
  short8v b8 = {b[0], b[1], b[2], b[3], 0, 0, 0, 0};
  return __builtin_amdgcn_mfma_f32_16x16x32_bf16(a8, b8, c, 0, 0, 0);
}
#endif

// ---------------- Kernel A: Abase[b*N+j][128] = mb1 + sum_{t,c<4} x[b,j,t,c]*mW1[5t+c][:]
__global__ __launch_bounds__(128) void kA(const float* __restrict__ x,
                                          const float* __restrict__ mW1,
                                          const float* __restrict__ mb1,
                                          float* __restrict__ Abase) {
  int bj = blockIdx.x;
  int k  = threadIdx.x;
  const float* xr = x + (size_t)bj * Tn * Fn;
  float acc = mb1[k];
#pragma unroll
  for (int t = 0; t < Tn; ++t)
#pragma unroll
    for (int c = 0; c < 4; ++c)
      acc = fmaf(xr[t * Fn + c], mW1[(t * 5 + c) * MH + k], acc);
  Abase[(size_t)bj * MH + k] = acc;
}

// ---------------- Kernel B: one block owns ALL 512 i for its (b, 4-j group).
// x row staged in LDS via full-line float4 loads (each HBM line touched by exactly
// one lane of one instruction -> no refetch amplification, the R6-R8 killer).
// Pipelined: j+1's global loads issue before j's compute (T14 split).
// GEMM1: P[khid][i'] = W1e^T(128x16) . E^T(16x32) + Abase   (K = t, padded 10->16)
// GEMM2: part[jsp][b][i][c] = sum_{j} relu(P)^T . W2        (K = khid, 8 x 16)
__global__ __launch_bounds__(1024, 8) void kB(const float* __restrict__ x,
                                              const float* __restrict__ Abase,
                                              const float* __restrict__ mW1,
                                              const float* __restrict__ mW2,
                                              __hip_bfloat16* __restrict__ part) {
  const int bx   = blockIdx.x;               // B * JSPLIT = 512
  const int jsp  = bx & (JSPLIT - 1);
  const int b    = bx >> 7;
  const int tid  = threadIdx.x;
  const int w    = tid >> 6;                 // wave 0..15 -> 32-wide i slice
  const int l    = tid & 63;
  const int ln   = l & 15;
  const int q    = l >> 4;
  const int ibase = w * 32;

  __shared__ float ciL[JPB][MH];                                  // 2 KB
  __shared__ __align__(16) float xt[XTF];                         // 20.6 KB x-row tile
  __shared__ __align__(16) __hip_bfloat16 stage[16][32 * MD];     // 32 KB

  // ---- cooperative stage: 4 rows x 128 floats, contiguous in Abase
  if (tid < JPB * MH / 4) {
    const float4* src = (const float4*)(Abase + (size_t)(b * Nn + jsp * JPB) * MH);
    ((float4*)&ciL[0][0])[tid] = src[tid];
  }

  // ---- A1 frags: A[m=khid][k=t] = W1e^T, zero for t>=10
  short4v A1[8];
#pragma unroll
  for (int mt = 0; mt < 8; ++mt) {
    float v[4];
#pragma unroll
    for (int e = 0; e < 4; ++e) {
      int t = q * 4 + e;
      v[e] = (t < Tn) ? mW1[(t * 5 + 4) * MH + mt * 16 + ln] : 0.f;
    }
    A1[mt] = pack4(v[0], v[1], v[2], v[3]);
  }
  // ---- B2 frags: B[k=khid][n=c] = W2 (8 k-tiles x 2 c-tiles)
  short4v B2[8][2];
#pragma unroll
  for (int kt = 0; kt < 8; ++kt)
#pragma unroll
    for (int ct = 0; ct < 2; ++ct) {
      float v[4];
#pragma unroll
      for (int e = 0; e < 4; ++e)
        v[e] = mW2[(kt * 16 + q * 4 + e) * MD + ct * 16 + ln];
      B2[kt][ct] = pack4(v[0], v[1], v[2], v[3]);
    }

  floatx4 acc[2][2];
#pragma unroll
  for (int a = 0; a < 2; ++a)
#pragma unroll
    for (int c = 0; c < 2; ++c) acc[a][c] = (floatx4)0.f;

  // ---- prologue: load j0's full x-row into registers (coalesced float4)
  float4 r0, r1;
  {
    const float4* xsrc = (const float4*)(x + (size_t)(b * Nn + jsp * JPB) * XTF);
    r0 = xsrc[tid];
    r1 = (tid < XTF / 4 - 1024) ? xsrc[1024 + tid] : make_float4(0.f, 0.f, 0.f, 0.f);
  }
  __syncthreads();   // ciL ready

#pragma unroll
  for (int jj = 0; jj < JPB; ++jj) {
    // ---- write tile jj from registers
    ((float4*)xt)[tid] = r0;
    if (tid < XTF / 4 - 1024) ((float4*)xt)[1024 + tid] = r1;
    __syncthreads();   // tile ready

    // ---- issue next j's global loads (latency hides under compute below)
    if (jj < JPB - 1) {
      const float4* xsrc =
          (const float4*)(x + (size_t)(b * Nn + jsp * JPB + jj + 1) * XTF);
      r0 = xsrc[tid];
      r1 = (tid < XTF / 4 - 1024) ? xsrc[1024 + tid] : make_float4(0.f, 0.f, 0.f, 0.f);
    }

    // ---- fragments from LDS: B[k=t][n=i'] = xt[t*Fn + 4 + i], zero t>=10.
    // bank math: addr = q*4*Fn + ... ; 4*Fn mod 32-banks = 16 -> 2 lanes/bank (free).
    short4v B1[2];
#pragma unroll
    for (int nt = 0; nt < 2; ++nt) {
      float v[4];
#pragma unroll
      for (int e = 0; e < 4; ++e) {
        int t = q * 4 + e;
        v[e] = (t < Tn) ? xt[t * Fn + 4 + ibase + nt * 16 + ln] : 0.f;
      }
      B1[nt] = pack4(v[0], v[1], v[2], v[3]);
    }

    // ---- chained GEMM1 -> relu/pack -> GEMM2 (registers only)
    // D1 row (4q+r) == A2 k (4q+e): packed D1 tile IS the GEMM2 A-frag.
#pragma unroll
    for (int mt = 0; mt < 8; ++mt) {
      floatx4 ci = *(const floatx4*)&ciL[jj][mt * 16 + q * 4];
      floatx4 d0 = MFMA16(A1[mt], B1[0], ci);
      floatx4 d1 = MFMA16(A1[mt], B1[1], ci);
      short4v pa0 = pack4(fmaxf(d0[0], 0.f), fmaxf(d0[1], 0.f),
                          fmaxf(d0[2], 0.f), fmaxf(d0[3], 0.f));
      short4v pa1 = pack4(fmaxf(d1[0], 0.f), fmaxf(d1[1], 0.f),
                          fmaxf(d1[2], 0.f), fmaxf(d1[3], 0.f));
      acc[0][0] = MFMA16(pa0, B2[mt][0], acc[0][0]);
      acc[0][1] = MFMA16(pa0, B2[mt][1], acc[0][1]);
      acc[1][0] = MFMA16(pa1, B2[mt][0], acc[1][0]);
      acc[1][1] = MFMA16(pa1, B2[mt][1], acc[1][1]);
    }
    __syncthreads();   // all tile reads done before next overwrite
  }

  // ---- epilogue: wave-private LDS stage, then fully-coalesced 16B/lane writes.
  __hip_bfloat16* st = &stage[w][0];
#pragma unroll
  for (int nt = 0; nt < 2; ++nt)
#pragma unroll
    for (int ct = 0; ct < 2; ++ct)
#pragma unroll
      for (int r = 0; r < 4; ++r)
        st[(nt * 16 + q * 4 + r) * MD + ct * 16 + ln] =
            __float2bfloat16(acc[nt][ct][r]);
  // wave-private tile: lgkmcnt ordering within the wave suffices, no barrier.
  const uint4* sv = (const uint4*)st;
  uint4 v0 = sv[l * 2];
  uint4 v1 = sv[l * 2 + 1];
  uint4* dst = (uint4*)(part + ((size_t)(jsp * Bn + b) * Nn + ibase) * MD);
  dst[l * 2]     = v0;
  dst[l * 2 + 1] = v1;
}

// ---------------- Kernel C: reduce 128 partials, then per (b,i) MLP 36 -> 128 -> 4
__global__ __launch_bounds__(128) void kC(const float* __restrict__ x,
                                          const __hip_bfloat16* __restrict__ part,
                                          const float* __restrict__ mb2,
                                          const float* __restrict__ iW1,
                                          const float* __restrict__ ib1,
                                          const float* __restrict__ iW2,
                                          const float* __restrict__ ib2,
                                          float* __restrict__ out) {
  int bi = blockIdx.x;          // b*N + i
  int b  = bi / Nn;
  int i  = bi - b * Nn;
  int k  = threadIdx.x;
  __shared__ float redp[4][MD];
  __shared__ float msL[MD];
  __shared__ float redo[UH][OD];

  // ---- partial reduction: thread (g,c), g = k>>5 handles jsp = g + 4*r
  {
    int c = k & (MD - 1);
    int g = k >> 5;
    float s = 0.f;
#pragma unroll 4
    for (int r = 0; r < JSPLIT / 4; ++r) {
      int jsp = g + 4 * r;
      s += (float)part[((size_t)(jsp * Bn + b) * Nn + i) * MD + c];
    }
    redp[g][c] = s;
  }
  __syncthreads();
  if (k < MD)
    msL[k] = redp[0][k] + redp[1][k] + redp[2][k] + redp[3][k] + (float)Nn * mb2[k];
  __syncthreads();

  const float* nf = x + ((size_t)bi * Tn + (Tn - 1)) * Fn;

  float a = ib1[k];
#pragma unroll
  for (int c = 0; c < MD; ++c)
    a = fmaf(msL[c], iW1[c * UH + k], a);
#pragma unroll
  for (int c = 0; c < 4; ++c)
    a = fmaf(nf[c], iW1[(MD + c) * UH + k], a);
  a = fmaxf(a, 0.f);
#pragma unroll
  for (int c = 0; c < OD; ++c) redo[k][c] = a * iW2[k * OD + c];
  __syncthreads();

  if (k < OD) {
    float s = ib2[k];
    for (int kk = 0; kk < UH; ++kk) s += redo[kk][k];
    out[(size_t)bi * OD + k] = s;
  }
}

extern "C" void kernel_launch(void* const* d_in, const int* in_sizes, int n_in,
                              void* d_out, int out_size, void* d_ws, size_t ws_size,
                              hipStream_t stream) {
  const float* x   = (const float*)d_in[0];
  const float* mW1 = (const float*)d_in[1];
  const float* mb1 = (const float*)d_in[2];
  const float* mW2 = (const float*)d_in[3];
  const float* mb2 = (const float*)d_in[4];
  const float* iW1 = (const float*)d_in[5];
  const float* ib1 = (const float*)d_in[6];
  const float* iW2 = (const float*)d_in[7];
  const float* ib2 = (const float*)d_in[8];
  float* out = (float*)d_out;

  float* Abase = (float*)d_ws;                                   // B*N*128 f32 = 1 MB
  __hip_bfloat16* part = (__hip_bfloat16*)(Abase + (size_t)Bn * Nn * MH);
  // part: JSPLIT*B*N*MD bf16 = 16.8 MB; fully written each call, no init needed.

  kA<<<Bn * Nn, 128, 0, stream>>>(x, mW1, mb1, Abase);
  kB<<<Bn * JSPLIT, 1024, 0, stream>>>(x, Abase, mW1, mW2, part);
  kC<<<Bn * Nn, 128, 0, stream>>>(x, part, mb2, iW1, ib1, iW2, ib2, out);
}

// Round 10
// 65.822 us; speedup vs baseline: 2.2828x; 2.2828x over previous
//
#include <hip/hip_runtime.h>
#include <hip/hip_bf16.h>

#define Bn 4
#define Nn 512
#define Tn 10
#define Fn 516      // N + 4
#define MH 128      // MSG_HID
#define MD 32       // MSG_DIM
#define UH 128      // UPD_HID
#define OD 4        // OUT_DIM

#define JSPLIT 64
#define JPB (Nn / JSPLIT)   // 8 j's per block
#define XTF (Tn * Fn)

typedef __attribute__((ext_vector_type(4))) short short4v;  // 4 bf16 = 2 VGPRs
typedef __attribute__((ext_vector_type(8))) short short8v;
typedef __attribute__((ext_vector_type(4))) float floatx4;

static __device__ inline unsigned pk2(float a, float b) {
  union { __hip_bfloat162 h; unsigned u; } cv;
  cv.h = __float22bfloat162_rn(make_float2(a, b));
  return cv.u;
}
static __device__ inline short4v pack4(float a, float b, float c, float d) {
  union { short4v s; unsigned u[2]; } cv;
  cv.u[0] = pk2(a, b);
  cv.u[1] = pk2(c, d);
  return cv.s;
}

// K=16 bf16 MFMA. A/B frag: lane(ln,q) elem e -> k = 4q+e. D: row m = 4q+r, col n = ln.
#if __has_builtin(__builtin_amdgcn_mfma_f32_16x16x16bf16_1k)
static __device__ inline floatx4 MFMA16(short4v a, short4v b, floatx4 c) {
  return __builtin_amdgcn_mfma_f32_16x16x16bf16_1k(a, b, c, 0, 0, 0);
}
#else
// Fallback: K=16 data in elems 0-3 of the K=32 op pairs k-wise; zero tail is exact.
static __device__ inline floatx4 MFMA16(short4v a, short4v b, floatx4 c) {
  short8v a8 = {a[0], a[1], a[2], a[3], 0, 0, 0, 0};
  short8v b8 = {b[0], b[1], b[2], b[3], 0, 0, 0, 0};
  return __builtin_amdgcn_mfma_f32_16x16x32_bf16(a8, b8, c, 0, 0, 0);
}
#endif

// ---------------- Kernel A: Abase[b*N+j][128] = mb1 + sum_{t,c<4} x[b,j,t,c]*mW1[5t+c][:]
// (reads only 40 floats per row -- trivial)
__global__ __launch_bounds__(128) void kA(const float* __restrict__ x,
                                          const float* __restrict__ mW1,
                                          const float* __restrict__ mb1,
                                          float* __restrict__ Abase) {
  int bj = blockIdx.x;
  int k  = threadIdx.x;
  const float* xr = x + (size_t)bj * Tn * Fn;
  float acc = mb1[k];
#pragma unroll
  for (int t = 0; t < Tn; ++t)
#pragma unroll
    for (int c = 0; c < 4; ++c)
      acc = fmaf(xr[t * Fn + c], mW1[(t * 5 + c) * MH + k], acc);
  Abase[(size_t)bj * MH + k] = acc;
}

// ---------------- Kernel E: Ex[(b*N+j)*N + i][16] = bf16(x[b,j,t,4+i]), t>=10 -> 0.
// Loads: coalesced 4B (one instr per 256B segment). Stores: wave-private LDS relay
// so each global store instruction writes 1KB fully contiguous.
__global__ __launch_bounds__(256) void kE(const float* __restrict__ x,
                                          __hip_bfloat16* __restrict__ Ex) {
  const int bj  = blockIdx.x;
  const int tid = threadIdx.x;
  const int w   = tid >> 6;
  const int l   = tid & 63;
  __shared__ uint4 rly[4][2][64];            // 8 KB, wave-private slices

  const float* xr = x + (size_t)bj * XTF + 4;
#pragma unroll
  for (int h = 0; h < 2; ++h) {
    int i = h * 256 + tid;
    float v[Tn];
#pragma unroll
    for (int t = 0; t < Tn; ++t) v[t] = xr[(size_t)t * Fn + i];

    union { unsigned u[8]; uint4 q[2]; } o;
#pragma unroll
    for (int p = 0; p < 5; ++p) o.u[p] = pk2(v[2 * p], v[2 * p + 1]);
    o.u[5] = 0u; o.u[6] = 0u; o.u[7] = 0u;

    rly[w][0][l] = o.q[0];                   // t 0..7
    rly[w][1][l] = o.q[1];                   // t 8..15
    // wave-private: compiler inserts lgkmcnt wait before the reads below.
    uint4* ob = (uint4*)(Ex + ((size_t)bj * Nn + h * 256 + w * 64) * 16);
    ob[l]      = rly[w][l & 1][l >> 1];
    ob[64 + l] = rly[w][l & 1][32 + (l >> 1)];
  }
}

// ---------------- Kernel B: register-chained MFMA pair-MLP (R4 geometry).
// GEMM1: P[khid][i'] = W1e^T(128x16) . E^T(16x32) + Abase   (K = t, padded 10->16)
// GEMM2: msum[i'][c] += relu(P)^T . W2                      (K = khid, 8 x 16)
// E-fragments are single short4v loads from the pre-packed Ex; all 16 loads for
// the block's 8 j's issue up front (deep ILP), full unroll.
__global__ __launch_bounds__(256, 4) void kB(const __hip_bfloat16* __restrict__ Ex,
                                             const float* __restrict__ Abase,
                                             const float* __restrict__ mW1,
                                             const float* __restrict__ mW2,
                                             float* __restrict__ msum) {
  const int bx    = blockIdx.x;              // B * 4 * JSPLIT = 1024
  const int jsp   = bx & (JSPLIT - 1);
  const int itile = (bx >> 6) & 3;
  const int b     = bx >> 8;
  const int tid   = threadIdx.x;
  const int w     = tid >> 6;                // wave -> 32-wide i slice
  const int l     = tid & 63;
  const int ln    = l & 15;
  const int q     = l >> 4;
  const int ibase = itile * 128 + w * 32;

  __shared__ float ciL[JPB][MH];             // 4 KB: Abase rows for this block's 8 j's
  {
    const float4* src = (const float4*)(Abase + (size_t)(b * Nn + jsp * JPB) * MH);
    ((float4*)&ciL[0][0])[tid] = src[tid];   // 256 float4 = 8x128 floats
  }

  // ---- all 16 E-frag loads issued up front (8 j x 2 nt), 8B each, coalesced
  short4v B1a[JPB][2];
#pragma unroll
  for (int jj = 0; jj < JPB; ++jj) {
    const __hip_bfloat16* ep =
        Ex + ((size_t)(b * Nn + jsp * JPB + jj) * Nn + ibase) * 16 + q * 4;
#pragma unroll
    for (int nt = 0; nt < 2; ++nt)
      B1a[jj][nt] = *(const short4v*)(ep + (nt * 16 + ln) * 16);
  }

  // ---- A1 frags: A[m=khid][k=t] = W1e^T, zero for t>=10
  short4v A1[8];
#pragma unroll
  for (int mt = 0; mt < 8; ++mt) {
    float v[4];
#pragma unroll
    for (int e = 0; e < 4; ++e) {
      int t = q * 4 + e;
      v[e] = (t < Tn) ? mW1[(t * 5 + 4) * MH + mt * 16 + ln] : 0.f;
    }
    A1[mt] = pack4(v[0], v[1], v[2], v[3]);
  }
  // ---- B2 frags: B[k=khid][n=c] = W2 (8 k-tiles x 2 c-tiles)
  short4v B2[8][2];
#pragma unroll
  for (int kt = 0; kt < 8; ++kt)
#pragma unroll
    for (int ct = 0; ct < 2; ++ct) {
      float v[4];
#pragma unroll
      for (int e = 0; e < 4; ++e)
        v[e] = mW2[(kt * 16 + q * 4 + e) * MD + ct * 16 + ln];
      B2[kt][ct] = pack4(v[0], v[1], v[2], v[3]);
    }

  floatx4 acc[2][2];
#pragma unroll
  for (int a = 0; a < 2; ++a)
#pragma unroll
    for (int c = 0; c < 2; ++c) acc[a][c] = (floatx4)0.f;

  __syncthreads();   // ciL ready

#pragma unroll
  for (int jj = 0; jj < JPB; ++jj) {
    // Chained GEMM1 -> relu/pack -> GEMM2, C-input from LDS.
    // D1 row (4q+r) == A2 k (4q+e): the packed D1 tile IS the GEMM2 A-frag.
#pragma unroll
    for (int mt = 0; mt < 8; ++mt) {
      floatx4 ci = *(const floatx4*)&ciL[jj][mt * 16 + q * 4];
      floatx4 d0 = MFMA16(A1[mt], B1a[jj][0], ci);
      floatx4 d1 = MFMA16(A1[mt], B1a[jj][1], ci);
      short4v pa0 = pack4(fmaxf(d0[0], 0.f), fmaxf(d0[1], 0.f),
                          fmaxf(d0[2], 0.f), fmaxf(d0[3], 0.f));
      short4v pa1 = pack4(fmaxf(d1[0], 0.f), fmaxf(d1[1], 0.f),
                          fmaxf(d1[2], 0.f), fmaxf(d1[3], 0.f));
      acc[0][0] = MFMA16(pa0, B2[mt][0], acc[0][0]);
      acc[0][1] = MFMA16(pa0, B2[mt][1], acc[0][1]);
      acc[1][0] = MFMA16(pa1, B2[mt][0], acc[1][0]);
      acc[1][1] = MFMA16(pa1, B2[mt][1], acc[1][1]);
    }
  }

  // ---- accumulate into msum: i = ibase + nt*16 + 4q + r, c = ct*16 + ln
#pragma unroll
  for (int nt = 0; nt < 2; ++nt)
#pragma unroll
    for (int ct = 0; ct < 2; ++ct)
#pragma unroll
      for (int r = 0; r < 4; ++r) {
        int i = ibase + nt * 16 + q * 4 + r;
        int c = ct * 16 + ln;
        atomicAdd(&msum[(size_t)(b * Nn + i) * MD + c], acc[nt][ct][r]);
      }
}

// ---------------- Kernel C: per (b,i) final MLP 36 -> 128 -> 4
__global__ __launch_bounds__(128) void kC(const float* __restrict__ x,
                                          const float* __restrict__ msum,
                                          const float* __restrict__ mb2,
                                          const float* __restrict__ iW1,
                                          const float* __restrict__ ib1,
                                          const float* __restrict__ iW2,
                                          const float* __restrict__ ib2,
                                          float* __restrict__ out) {
  int bi = blockIdx.x;
  int k  = threadIdx.x;
  __shared__ float red[UH][OD];

  const float* ms = msum + (size_t)bi * MD;
  const float* nf = x + ((size_t)bi * Tn + (Tn - 1)) * Fn;

  float a = ib1[k];
#pragma unroll
  for (int c = 0; c < MD; ++c)
    a = fmaf(ms[c] + (float)Nn * mb2[c], iW1[c * UH + k], a);
#pragma unroll
  for (int c = 0; c < 4; ++c)
    a = fmaf(nf[c], iW1[(MD + c) * UH + k], a);
  a = fmaxf(a, 0.f);
#pragma unroll
  for (int c = 0; c < OD; ++c) red[k][c] = a * iW2[k * OD + c];
  __syncthreads();

  if (k < OD) {
    float s = ib2[k];
    for (int kk = 0; kk < UH; ++kk) s += red[kk][k];
    out[(size_t)bi * OD + k] = s;
  }
}

extern "C" void kernel_launch(void* const* d_in, const int* in_sizes, int n_in,
                              void* d_out, int out_size, void* d_ws, size_t ws_size,
                              hipStream_t stream) {
  const float* x   = (const float*)d_in[0];
  const float* mW1 = (const float*)d_in[1];
  const float* mb1 = (const float*)d_in[2];
  const float* mW2 = (const float*)d_in[3];
  const float* mb2 = (const float*)d_in[4];
  const float* iW1 = (const float*)d_in[5];
  const float* ib1 = (const float*)d_in[6];
  const float* iW2 = (const float*)d_in[7];
  const float* ib2 = (const float*)d_in[8];
  float* out = (float*)d_out;

  float* Abase = (float*)d_ws;                                   // 1 MB
  float* msum  = Abase + (size_t)Bn * Nn * MH;                   // 256 KB
  __hip_bfloat16* Ex = (__hip_bfloat16*)(msum + (size_t)Bn * Nn * MD);  // 33.5 MB

  hipMemsetAsync(msum, 0, (size_t)Bn * Nn * MD * sizeof(float), stream);

  kA<<<Bn * Nn, 128, 0, stream>>>(x, mW1, mb1, Abase);
  kE<<<Bn * Nn, 256, 0, stream>>>(x, Ex);
  kB<<<Bn * 4 * JSPLIT, 256, 0, stream>>>(Ex, Abase, mW1, mW2, msum);
  kC<<<Bn * Nn, 128, 0, stream>>>(x, msum, mb2, iW1, ib1, iW2, ib2, out);
}